// Round 3
// baseline (1643.510 us; speedup 1.0000x reference)
//
#include <hip/hip_runtime.h>
#include <math.h>

// Problem: MPMatcher  S=6, B=16, L=8, M=256, K=128
// Phase 1 (PASSING, DO NOT TOUCH): cost f32, ocml logf, *(1/6) reciprocal mean.
// Phase 2: reference's buggy greedy walk, f64-exact. R14:
//   - candidate QUEUE depth 2 (head, Q): each iteration STARTS a ladder-B
//     refill whose result is consumed one march LATER -> ladder B latency
//     spans a full iteration and leaves the march critical chain entirely.
//     March chain = decide -> (u,cc from queue regs, ready) -> ladder A only.
//   - candidate rows pre-loaded into registers (ccH/ccQ/ccN) >=2 marches ahead
//   - Dcons deferral (proven R12): consumed dummies logged (clog) and updated
//     at commit with amt = usum_final - Dcons[t]; no per-iteration dummy dual
//     updates; dummy v (vd_lds) and u snapshots frozen in registers walk-long
//   - real side unchanged from R11: value-DPP ladder + ballot extraction (R9),
//     register u accumulation (R9), rows 1..128 pre-matched (R8)

#define S_ 6
#define B_ 16
#define L_ 8
#define M_ 256
#define K_ 128

// ---------------------------------------------------------------- cost kernel
__global__ void cost_kernel(const float* __restrict__ mp,   // (6,16,8,256,2)
                            const float* __restrict__ mv,   // (6,16,256,1)
                            const float* __restrict__ gt,   // (6,16,128,2)
                            const float* __restrict__ gv,   // (6,16,128,1)
                            float* __restrict__ cost)       // (16,256,128)
{
#pragma clang fp contract(off)
    const int b = blockIdx.x;
    const int m = blockIdx.y;
    const int k = threadIdx.x;

    float accS = 0.0f;
    for (int s = 0; s < S_; ++s) {
        const int sb = s * B_ + b;
        const float gx = gt[(sb * K_ + k) * 2 + 0];
        const float gy = gt[(sb * K_ + k) * 2 + 1];
        float accL = 0.0f;
#pragma unroll
        for (int l = 0; l < L_; ++l) {
            const int base = ((sb * L_ + l) * M_ + m) * 2;
            const float dx = fabsf(mp[base + 0] - gx);
            const float dy = fabsf(mp[base + 1] - gy);
            const float diff = dx + dy;
            const float dl = (float)(L_ - (l + 1)) * 0.05f;
            const float t = diff - dl;
            accL += fmaxf(t, 0.0f);
        }
        const float meanL = accL * 0.125f;
        const float mvv = mv[sb * M_ + m];
        const float gtv = gv[sb * K_ + k];
        const float lp = -logf(mvv);
        const float ln = -logf(1.0f - mvv);
        const float val = (gtv != 0.0f) ? (5.0f * meanL + lp) : ln;
        accS += val;
    }
    cost[(b * M_ + m) * K_ + k] = accS * (1.0f / 6.0f);
}

// --------------------------------------------------------------- bit helpers
__device__ __forceinline__ double bits2d(int lo, int hi) {
    const unsigned long long u =
        ((unsigned long long)(unsigned)hi << 32) | (unsigned)lo;
    return __longlong_as_double((long long)u);
}
__device__ __forceinline__ void d2bits(double d, int& lo, int& hi) {
    const unsigned long long u = (unsigned long long)__double_as_longlong(d);
    lo = (int)(u & 0xffffffffull);
    hi = (int)(u >> 32);
}
__device__ __forceinline__ double readlane_d(double d, int l) {
    int lo, hi; d2bits(d, lo, hi);
    return bits2d(__builtin_amdgcn_readlane(lo, l),
                  __builtin_amdgcn_readlane(hi, l));
}

// one DPP reduction stage on a (lo,hi) f64 register pair with combiner FOP
#define RSTG(LOV, HIV, FOP, CTRL, RM)                                            \
    {                                                                            \
        const int nlo_ = __builtin_amdgcn_update_dpp(LOV, LOV, CTRL, RM, 0xf, false); \
        const int nhi_ = __builtin_amdgcn_update_dpp(HIV, HIV, CTRL, RM, 0xf, false); \
        const double r_ = FOP(bits2d(LOV, HIV), bits2d(nlo_, nhi_));             \
        d2bits(r_, LOV, HIV);                                                    \
    }
// full 64-lane ladder (result in lane 63)
#define RLADDER(LOV, HIV, FOP)                                                   \
    RSTG(LOV, HIV, FOP, 0x111, 0xf)  /* row_shr:1  */                            \
    RSTG(LOV, HIV, FOP, 0x112, 0xf)  /* row_shr:2  */                            \
    RSTG(LOV, HIV, FOP, 0x114, 0xf)  /* row_shr:4  */                            \
    RSTG(LOV, HIV, FOP, 0x118, 0xf)  /* row_shr:8  */                            \
    RSTG(LOV, HIV, FOP, 0x142, 0xa)  /* row_bcast:15 -> rows 1,3 */              \
    RSTG(LOV, HIV, FOP, 0x143, 0xc)  /* row_bcast:31 -> rows 2,3 */

// select best free dummy by (v desc, j asc), excluding used bits and cols
// EXJ1/EXJ2 (pass -1 for none). Outputs: JOUT (col), VOUT (v), UOUT (u of its
// row, walk-start snapshot). Exhausted set -> VOUT = -INF (never consumed:
// dval = (0-u)-(-INF) = +INF, real always wins).
#define SELBEST(EXJ1, EXJ2, JOUT, VOUT, UOUT)                                    \
    {                                                                            \
        const double vm2_ = ((used & 4) || (jd2 == (EXJ1)) || (jd2 == (EXJ2)))   \
                                ? NINF : v2;                                     \
        const double vm3_ = ((used & 8) || (jd3 == (EXJ1)) || (jd3 == (EXJ2)))   \
                                ? NINF : v3;                                     \
        const double bx_ = fmax(vm2_, vm3_);                                     \
        int xlo_, xhi_; d2bits(bx_, xlo_, xhi_);                                 \
        RLADDER(xlo_, xhi_, fmax)                                                \
        VOUT = bits2d(__builtin_amdgcn_readlane(xlo_, 63),                       \
                      __builtin_amdgcn_readlane(xhi_, 63));                      \
        int jc_ = BIG;                                                           \
        if (vm3_ == VOUT) jc_ = jd3;                                             \
        if (vm2_ == VOUT) jc_ = jd2;   /* lower j wins within lane */            \
        const unsigned long long bd_ = __ballot(jc_ != BIG);                     \
        JOUT = __builtin_amdgcn_readlane(jc_, (int)__builtin_ctzll(bd_));        \
        const int ol_ = ((JOUT) - 129) >> 1, sl_ = ((JOUT) - 129) & 1;           \
        UOUT = readlane_d(sl_ ? up3 : up2, ol_);                                 \
    }

// ------------------------------------------------------------- matcher kernel
// One wave per batch. Lane owns real cols j=2*lane+1, 2*lane+2 (slots 0,1)
// and dummy cols j=2*lane+129, 2*lane+130 (slots 2,3).
__global__ __launch_bounds__(64, 1) void match_kernel(const float* __restrict__ cost,
                                                      int* __restrict__ out)
{
#pragma clang fp contract(off)
    const int b = blockIdx.x;
    const int lane = threadIdx.x;   // 0..63
    const float* C = cost + (size_t)b * M_ * K_;
    const double INF = __builtin_inf();
    const double NINF = -__builtin_inf();
    const int BIG = 0x7fffffff;

    __shared__ float  C_lds[M_ * K_];   // 128 KB cost slab (row-major, = global)
    __shared__ double u_lds[257];       // u[0..256], 1-based rows
    __shared__ int    p_lds[257];       // p[j] = row matched to col j; 0 = free
    __shared__ double vd_lds[128];      // v of dummy cols 129..256
    __shared__ double Dcons[128];       // usum at consumption of log slot t
    __shared__ int    clog[128];        // consumption log: dummy col j

    // stage the batch's cost slab into LDS (coalesced float4 copies)
    for (int t = lane; t < (M_ * K_) / 4; t += 64)
        ((float4*)C_lds)[t] = ((const float4*)C)[t];

    // rows 1..128 pre-matched to dummy cols 129..256 (exact, proven R8)
    for (int t = lane; t < 257; t += 64) {
        u_lds[t] = 0.0;
        p_lds[t] = (t >= 129) ? (t - 128) : 0;
    }
    for (int t = lane; t < 128; t += 64) vd_lds[t] = 0.0;
    __syncthreads();

    double v0 = 0.0, v1 = 0.0;        // real column potentials (persist)
    const int jd2 = 2 * lane + 129;   // this lane's dummy cols
    const int jd3 = 2 * lane + 130;

    for (int i = 129; i <= 256; ++i) {
        // ---- row start: snapshots (p static during walk; u[p[j]] of cols not
        // yet used never updated mid-walk -> snapshots valid, proven R11).
        // Dummy v (vd_lds) frozen during a walk -> register copies v2/v3.
        const int pj0 = p_lds[2 * lane + 1];
        const int pj1 = p_lds[2 * lane + 2];
        double ur0 = u_lds[pj0], ur1 = u_lds[pj1];
        const double up0 = ur0, up1 = ur1;
        const double up2 = u_lds[2 * lane + 1];   // u of dummy jd2's row
        const double up3 = u_lds[2 * lane + 2];   // u of dummy jd3's row
        const double v2 = vd_lds[2 * lane];
        const double v3 = vd_lds[2 * lane + 1];

        float2 cc = *(const float2*)(C_lds + (i - 1) * K_ + 2 * lane);
        double u_i0 = 0.0;
        int used = 0;      // bits: 1,2 = real slots; 4,8 = dummy consumed
        double usum = 0.0;
        int j1 = 0;
        int ptr = 0;       // consumption-log length (wave-uniform)

        // ---- prologue: fill the 2-entry candidate queue (head, Q)
        int jdH, jdQ, jdN; double vdH, vdQ, vdN, udH, udQ, udN;
        SELBEST(-1, -1, jdH, vdH, udH)
        SELBEST(jdH, -1, jdQ, vdQ, udQ)
        float2 ccH = *(const float2*)(C_lds + (jdH - 129) * K_ + 2 * lane);
        float2 ccQ = *(const float2*)(C_lds + (jdQ - 129) * K_ + 2 * lane);
        double dval = (0.0 - u_i0) - vdH;

        for (;;) {
            // ---- ladder A: real-side min for the current row (the only
            // latency on the march chain; inputs all ready at iteration top)
            double cd0 = ((double)cc.x - u_i0) - v0;
            double cd1 = ((double)cc.y - u_i0) - v1;
            if (used & 1) cd0 = INF;
            if (used & 2) cd1 = INF;
            double bv = fmin(cd0, cd1);
            int lo, hi; d2bits(bv, lo, hi);
            RLADDER(lo, hi, fmin)
            const double rmin = bits2d(__builtin_amdgcn_readlane(lo, 63),
                                       __builtin_amdgcn_readlane(hi, 63));

            // ---- ladder B: refill candidate, consumed on the NEXT march ->
            // its latency (ladder+extraction+u-readlanes+row-load) spans a
            // full iteration, off the critical chain
            SELBEST(jdH, jdQ, jdN, vdN, udN)
            const float2 ccN = *(const float2*)(C_lds + (jdN - 129) * K_ + 2 * lane);

            // ref argmin = lowest j among global-min achievers; real j < dummy
            // j, and dval = min over free dummies (fl subtraction is monotone)
            if (rmin <= dval) {
                // ---- real column wins
                const double delta = rmin;
                usum += delta;
                if (used & 1) { ur0 += delta; v0 -= delta; }
                if (used & 2) { ur1 += delta; v1 -= delta; }

                int jr = BIG;
                if (cd1 == delta) jr = 2 * lane + 2;
                if (cd0 == delta) jr = 2 * lane + 1;
                const unsigned long long br = __ballot(jr != BIG);
                j1 = __builtin_amdgcn_readlane(jr, (int)__builtin_ctzll(br));

                const int ol = (j1 - 1) >> 1, sl = (j1 - 1) & 1;
                const int psel = sl ? pj1 : pj0;
                const int i0n = __builtin_amdgcn_readlane(psel, ol);
                if (i0n == 0) break;    // free real column -> augment (way==0)

                const double u_n = readlane_d(sl ? up1 : up0, ol);
                if (lane == ol) used |= (1 << sl);   // ref marks at next top
                u_i0 = u_n;
                cc = *(const float2*)(C_lds + (i0n - 1) * K_ + 2 * lane);
                dval = (0.0 - u_i0) - vdH;
                // queue unchanged; jdN discarded (next iteration's refill
                // recomputes it identically: exclusions unchanged)
            } else {
                // ---- march through head: everything pre-staged in registers
                const double delta = dval;
                usum += delta;
                if (used & 1) { ur0 += delta; v0 -= delta; }
                if (used & 2) { ur1 += delta; v1 -= delta; }
                // consumed-dummy dual updates deferred (R12 Dcons, proven)
                if (lane == 0) { clog[ptr] = jdH; Dcons[ptr] = usum; }
                ++ptr;
                const int olc = (jdH - 129) >> 1, slc = (jdH - 129) & 1;
                if (lane == olc) used |= (4 << slc);
                j1 = jdH;
                u_i0 = udH;            // row-start u snapshot from the record
                cc = ccH;              // pre-loaded >=2 iterations ago
                jdH = jdQ; vdH = vdQ; udH = udQ; ccH = ccQ;
                jdQ = jdN; vdQ = vdN; udQ = udN; ccQ = ccN;
                dval = (0.0 - u_i0) - vdH;
            }
        }

        // ---- commit: real used slots write running u; consumed dummies get
        // deferred suffix updates amt = usum_final - Dcons[t]; lane 0 augments
        __syncthreads();
        if (used & 1) u_lds[pj0] = ur0;
        if (used & 2) u_lds[pj1] = ur1;
        {
            const int t0 = 2 * lane, t1 = 2 * lane + 1;
            if (t0 < ptr) {
                const int j = clog[t0];
                const double amt = usum - Dcons[t0];
                u_lds[j - 128] += amt;
                vd_lds[j - 129] -= amt;
            }
            if (t1 < ptr) {
                const int j = clog[t1];
                const double amt = usum - Dcons[t1];
                u_lds[j - 128] += amt;
                vd_lds[j - 129] -= amt;
            }
        }
        if (lane == 0) { p_lds[j1] = i; u_lds[i] = usum; }
        __syncthreads();
    }

    // out[b][k] = p[k+1] - 1 for the K real columns
    for (int j = lane; j < K_; j += 64)
        out[b * K_ + j] = p_lds[j + 1] - 1;
}

// ------------------------------------------------------------------- launcher
extern "C" void kernel_launch(void* const* d_in, const int* in_sizes, int n_in,
                              void* d_out, int out_size, void* d_ws, size_t ws_size,
                              hipStream_t stream) {
    const float* mp = (const float*)d_in[0];   // meta_points
    const float* mv = (const float*)d_in[1];   // meta_visibles
    /* d_in[2] covisibles: unused by reference */
    const float* gt = (const float*)d_in[3];   // gtpoints
    const float* gv = (const float*)d_in[4];   // gtvisibles
    int* out = (int*)d_out;                    // int32 assignment indices
    float* cost = (float*)d_ws;                // 16*256*128 fp32 = 2 MB

    dim3 gridA(B_, M_);
    cost_kernel<<<gridA, K_, 0, stream>>>(mp, mv, gt, gv, cost);
    match_kernel<<<B_, 64, 0, stream>>>(cost, out);
}

// Round 4
// 1362.846 us; speedup vs baseline: 1.2059x; 1.2059x over previous
//
#include <hip/hip_runtime.h>
#include <math.h>

// Problem: MPMatcher  S=6, B=16, L=8, M=256, K=128
// Phase 1 (PASSING, DO NOT TOUCH): cost f32, ocml logf, *(1/6) reciprocal mean.
// Phase 2: reference's buggy greedy walk, f64-exact. R15 = R11 structure +
// fully-deferred dual updates (instruction diet; wave issue is in-order and
// f64 is half-rate, so per-iteration f64 count is the bottleneck):
//   - the 8 conditional per-iteration f64 update ops (ur+=delta, v-=delta for
//     used slots) are REMOVED from the loop. Used cols are INF-masked from the
//     min and free cols' duals never change mid-walk, so the updates are
//     unobservable until commit. Column chosen at running-sum U_j receives
//     amt = usum_final - U_j at commit (same regrouping class as R12/R14's
//     Dcons deferral, which passed absmax=0 twice).
//   - owner lane records U_j (register snapshot) at the existing used|=bit site
//   - commit: u[p[j]] = up_j + amt; v_j -= amt  (per-lane, no conflicts)
//   - everything else byte-identical to R11: software-pipelined row load,
//     value-DPP ladder + ballot extraction (R9), rows 1..128 pre-matched (R8),
//     dummies never re-matched -> i0n = j1-128 and static dummy p indices

#define S_ 6
#define B_ 16
#define L_ 8
#define M_ 256
#define K_ 128

// ---------------------------------------------------------------- cost kernel
__global__ void cost_kernel(const float* __restrict__ mp,   // (6,16,8,256,2)
                            const float* __restrict__ mv,   // (6,16,256,1)
                            const float* __restrict__ gt,   // (6,16,128,2)
                            const float* __restrict__ gv,   // (6,16,128,1)
                            float* __restrict__ cost)       // (16,256,128)
{
#pragma clang fp contract(off)
    const int b = blockIdx.x;
    const int m = blockIdx.y;
    const int k = threadIdx.x;

    float accS = 0.0f;
    for (int s = 0; s < S_; ++s) {
        const int sb = s * B_ + b;
        const float gx = gt[(sb * K_ + k) * 2 + 0];
        const float gy = gt[(sb * K_ + k) * 2 + 1];
        float accL = 0.0f;
#pragma unroll
        for (int l = 0; l < L_; ++l) {
            const int base = ((sb * L_ + l) * M_ + m) * 2;
            const float dx = fabsf(mp[base + 0] - gx);
            const float dy = fabsf(mp[base + 1] - gy);
            const float diff = dx + dy;
            const float dl = (float)(L_ - (l + 1)) * 0.05f;
            const float t = diff - dl;
            accL += fmaxf(t, 0.0f);
        }
        const float meanL = accL * 0.125f;
        const float mvv = mv[sb * M_ + m];
        const float gtv = gv[sb * K_ + k];
        const float lp = -logf(mvv);
        const float ln = -logf(1.0f - mvv);
        const float val = (gtv != 0.0f) ? (5.0f * meanL + lp) : ln;
        accS += val;
    }
    cost[(b * M_ + m) * K_ + k] = accS * (1.0f / 6.0f);
}

// --------------------------------------------------------------- bit helpers
__device__ __forceinline__ double bits2d(int lo, int hi) {
    const unsigned long long u =
        ((unsigned long long)(unsigned)hi << 32) | (unsigned)lo;
    return __longlong_as_double((long long)u);
}
__device__ __forceinline__ void d2bits(double d, int& lo, int& hi) {
    const unsigned long long u = (unsigned long long)__double_as_longlong(d);
    lo = (int)(u & 0xffffffffull);
    hi = (int)(u >> 32);
}

// ------------------------------------------------------------- matcher kernel
// One wave per batch. Lane owns real cols j=2*lane+1, 2*lane+2 (slots 0,1)
// and dummy cols j=2*lane+129, 2*lane+130 (slots 2,3).
__global__ __launch_bounds__(64, 1) void match_kernel(const float* __restrict__ cost,
                                                      int* __restrict__ out)
{
#pragma clang fp contract(off)
    const int b = blockIdx.x;
    const int lane = threadIdx.x;   // 0..63
    const float* C = cost + (size_t)b * M_ * K_;
    const double INF = __builtin_inf();
    const int BIG = 0x7fffffff;

    __shared__ float  C_lds[M_ * K_];   // 128 KB cost slab (row-major, = global)
    __shared__ double u_lds[257];       // u[0..256], 1-based rows
    __shared__ int    p_lds[257];       // p[j] = row matched to col j; 0 = free

    // stage the batch's cost slab into LDS (coalesced float4 copies)
    for (int t = lane; t < (M_ * K_) / 4; t += 64)
        ((float4*)C_lds)[t] = ((const float4*)C)[t];

    // rows 1..128 pre-matched to dummy cols 129..256 (exact, proven R8)
    for (int t = lane; t < 257; t += 64) {
        u_lds[t] = 0.0;
        p_lds[t] = (t >= 129) ? (t - 128) : 0;
    }
    __syncthreads();

    double v0 = 0.0, v1 = 0.0, v2 = 0.0, v3 = 0.0;  // column potentials

    for (int i = 129; i <= 256; ++i) {
        // ---- row start: snapshot caches. p static during walk; dummies never
        // re-matched (p[dummy j] = j-128 statically); u[p[j]] for free cols
        // never updated mid-walk -> snapshots valid for broadcasts.
        const int pj0 = p_lds[2 * lane + 1];
        const int pj1 = p_lds[2 * lane + 2];
        const double up0 = u_lds[pj0], up1 = u_lds[pj1];
        const double up2 = u_lds[2 * lane + 1];   // p[2*lane+129] = 2*lane+1
        const double up3 = u_lds[2 * lane + 2];   // p[2*lane+130] = 2*lane+2

        float2 cc = *(const float2*)(C_lds + (i - 1) * K_ + 2 * lane);
        double u_i0 = 0.0;
        int used = 0;
        int j1 = 0;
        double usum = 0.0;
        // usum snapshot at choice time for each owned slot (valid iff used bit)
        double Ua0 = 0.0, Ua1 = 0.0, Ua2 = 0.0, Ua3 = 0.0;

        for (;;) {
            // candidates: cur = (cost - u[i0]) - v   (exact ref op order, f64)
            double cd0 = ((double)cc.x - u_i0) - v0;
            double cd1 = ((double)cc.y - u_i0) - v1;
            double cd2 = (0.0 - u_i0) - v2;
            double cd3 = (0.0 - u_i0) - v3;
            if (used & 1) cd0 = INF;
            if (used & 2) cd1 = INF;
            if (used & 4) cd2 = INF;
            if (used & 8) cd3 = INF;

            // local value min (+-0 ambiguity harmless, proven R9/R10)
            const double m01 = fmin(cd0, cd1);
            const double m23 = fmin(cd2, cd3);
            double bv = fmin(m01, m23);

            // wave value-min via DPP ladder (VALU pipe), result in lane 63
            int lo, hi; d2bits(bv, lo, hi);
#define MIN_STAGE(CTRL, RM)                                                      \
            {                                                                    \
                const int nlo = __builtin_amdgcn_update_dpp(lo, lo, CTRL, RM, 0xf, false); \
                const int nhi = __builtin_amdgcn_update_dpp(hi, hi, CTRL, RM, 0xf, false); \
                const double mv2 = fmin(bits2d(lo, hi), bits2d(nlo, nhi));       \
                d2bits(mv2, lo, hi);                                             \
            }
            MIN_STAGE(0x111, 0xf)   // row_shr:1
            MIN_STAGE(0x112, 0xf)   // row_shr:2
            MIN_STAGE(0x114, 0xf)   // row_shr:4
            MIN_STAGE(0x118, 0xf)   // row_shr:8
            MIN_STAGE(0x142, 0xa)   // row_bcast:15 -> rows 1,3
            MIN_STAGE(0x143, 0xc)   // row_bcast:31 -> rows 2,3
#undef MIN_STAGE
            const int mlo = __builtin_amdgcn_readlane(lo, 63);
            const int mhi = __builtin_amdgcn_readlane(hi, 63);
            const double delta = bits2d(mlo, mhi);   // == min value (scalar)

            // first-index extraction: cd == delta marks min-achievers; lane
            // order == j order within each class; real js (<=128) < dummy js
            int jr = BIG;
            if (cd1 == delta) jr = 2 * lane + 2;
            if (cd0 == delta) jr = 2 * lane + 1;
            int jd = BIG;
            if (cd3 == delta) jd = 2 * lane + 130;
            if (cd2 == delta) jd = 2 * lane + 129;
            const unsigned long long br = __ballot(jr != BIG);
            const unsigned long long bd = __ballot(jd != BIG);
            const unsigned long long bb = br ? br : bd;
            const int cand = (br != 0ull) ? jr : jd;
            j1 = __builtin_amdgcn_readlane(cand, (int)__builtin_ctzll(bb));

            // next row: dummies are never re-matched -> p[j1] = j1-128 statically
            int ol, sl;
            if (j1 >= 129) { ol = (j1 - 129) >> 1; sl = 2 + ((j1 - 129) & 1); }
            else           { ol = (j1 - 1) >> 1;   sl = (j1 - 1) & 1; }
            const int psel = (sl == 0) ? pj0 : (sl == 1) ? pj1 : 0;
            const int i0n = (j1 >= 129) ? (j1 - 128)
                                        : __builtin_amdgcn_readlane(psel, ol);

            // speculative next-row load, issued ASAP (clamped; unused on break)
            const int rown = (i0n > 0 ? i0n : 1) - 1;
            const float2 ccn = *(const float2*)(C_lds + rown * K_ + 2 * lane);

            // ---- shadow work (under the load's latency) ----
            // duals are NOT updated per-iteration (deferred to commit); only
            // the running delta-sum advances (ref-equivalent: used cols are
            // INF-masked and free cols' duals never change mid-walk)
            usum += delta;

            // u[p[j1]] broadcast from owner's row-start snapshot
            const double usel = (sl == 0) ? up0 : (sl == 1) ? up1
                              : (sl == 2) ? up2 : up3;
            int ulo, uhi; d2bits(usel, ulo, uhi);
            const double u_n = bits2d(__builtin_amdgcn_readlane(ulo, ol),
                                      __builtin_amdgcn_readlane(uhi, ol));

            if (i0n == 0) break;    // free real column -> augment (way==0)

            // mark j1 used (it is j0 of the next iteration, ref marks at top)
            // and snapshot the running sum for the deferred update
            if (lane == ol) {
                used |= (1 << sl);
                if (sl == 0)      Ua0 = usum;
                else if (sl == 1) Ua1 = usum;
                else if (sl == 2) Ua2 = usum;
                else              Ua3 = usum;
            }
            u_i0 = u_n;
            cc = ccn;
        }

        // ---- commit: deferred dual updates. Column j chosen at snapshot U_j
        // accumulates amt = usum_final - U_j (== sum of all later deltas).
        // Distinct columns -> distinct rows -> no LDS write conflicts.
        __syncthreads();
        if (used & 1) { const double a = usum - Ua0; u_lds[pj0] = up0 + a; v0 -= a; }
        if (used & 2) { const double a = usum - Ua1; u_lds[pj1] = up1 + a; v1 -= a; }
        if (used & 4) { const double a = usum - Ua2; u_lds[2 * lane + 1] = up2 + a; v2 -= a; }
        if (used & 8) { const double a = usum - Ua3; u_lds[2 * lane + 2] = up3 + a; v3 -= a; }
        if (lane == 0) { p_lds[j1] = i; u_lds[i] = usum; }
        __syncthreads();
    }

    // out[b][k] = p[k+1] - 1 for the K real columns
    for (int j = lane; j < K_; j += 64)
        out[b * K_ + j] = p_lds[j + 1] - 1;
}

// ------------------------------------------------------------------- launcher
extern "C" void kernel_launch(void* const* d_in, const int* in_sizes, int n_in,
                              void* d_out, int out_size, void* d_ws, size_t ws_size,
                              hipStream_t stream) {
    const float* mp = (const float*)d_in[0];   // meta_points
    const float* mv = (const float*)d_in[1];   // meta_visibles
    /* d_in[2] covisibles: unused by reference */
    const float* gt = (const float*)d_in[3];   // gtpoints
    const float* gv = (const float*)d_in[4];   // gtvisibles
    int* out = (int*)d_out;                    // int32 assignment indices
    float* cost = (float*)d_ws;                // 16*256*128 fp32 = 2 MB

    dim3 gridA(B_, M_);
    cost_kernel<<<gridA, K_, 0, stream>>>(mp, mv, gt, gv, cost);
    match_kernel<<<B_, 64, 0, stream>>>(cost, out);
}